// Round 5
// baseline (82.438 us; speedup 1.0000x reference)
//
#include <hip/hip_runtime.h>
#include <hip/hip_bf16.h>
#include <cstdint>

// Problem constants (ConceptBoxModel): B=256, L=512, N=64, D=32, C=100
constexpr int Bb = 256, Ll = 512, Nn = 64, Dd = 32, Cc = 100;
constexpr float EPS = 1e-6f;

// ---------------------------------------------------------------------------
// Kernel A v3: x_m = h@Wc + bc ; delta = softplus(h@Wo + bo) ; p_hat
// grid (n=64 fast, bt=8 slow) = 512 blocks x 256 thr -> 2 blocks/CU.
// Same-n blocks share an XCD (n&7) so each XCD's L2 caches only 8 W-slices.
// Block tile: 32 b-rows x (32 d x 2 mats).  Thread: 2r x 2d x 2mats = 8 FMA/kk.
// ---------------------------------------------------------------------------
__global__ __launch_bounds__(256) void kA(
    const float* __restrict__ h,    // [256][512]
    const float* __restrict__ Wc,   // [64][512][32]
    const float* __restrict__ bc,   // [64][32]
    const float* __restrict__ Wo,
    const float* __restrict__ bo,
    const float* __restrict__ Wp,   // [64][64]
    const float* __restrict__ bp,   // [64]
    float* __restrict__ xm_ws,      // [256][64][32]
    float* __restrict__ dl_ws,      // [256][64][32]
    float* __restrict__ ph_ws,      // [256][64]
    float* __restrict__ out_ph)     // [256][64]
{
  const int n  = blockIdx.x;
  const int bt = blockIdx.y * 32;
  const int t  = threadIdx.x;     // 0..255
  const int tx = t & 15;          // col pair: d0 = 2*tx (both mats)
  const int ty = t >> 4;          // row pair: bt + 2*ty, +1
  const int d0 = tx * 2;

  __shared__ float hsT[32][36];   // [kk][row], pad 36 (b64-aligned rows)
  __shared__ float wcs[32][32];   // [kk][d]
  __shared__ float wos[32][32];

  float ac[2][2] = {};   // [row][col] for Wc
  float ao[2][2] = {};   // for Wo

  const int sr = t >> 3, sk4 = (t & 7) * 4;   // h staging: row, kk quad
  const float* wcb = Wc + n * (Ll * Dd);
  const float* wob = Wo + n * (Ll * Dd);

  for (int k0 = 0; k0 < Ll; k0 += 32) {
    __syncthreads();
    // stage h tile transposed: hsT[kk][row]
    {
      float4 hv = *(const float4*)(h + (bt + sr) * Ll + k0 + sk4);
      hsT[sk4 + 0][sr] = hv.x; hsT[sk4 + 1][sr] = hv.y;
      hsT[sk4 + 2][sr] = hv.z; hsT[sk4 + 3][sr] = hv.w;
    }
    // stage W tiles (32x32 contiguous in memory)
    {
      float4 wv = *(const float4*)(wcb + k0 * Dd + t * 4);
      float4 ov = *(const float4*)(wob + k0 * Dd + t * 4);
      *(float4*)(&wcs[0][0] + t * 4) = wv;
      *(float4*)(&wos[0][0] + t * 4) = ov;
    }
    __syncthreads();
    #pragma unroll
    for (int kk = 0; kk < 32; kk++) {
      const float2 hv = *(const float2*)&hsT[kk][ty * 2];
      const float2 wc = *(const float2*)&wcs[kk][d0];
      const float2 wo = *(const float2*)&wos[kk][d0];
      ac[0][0] += hv.x * wc.x; ac[0][1] += hv.x * wc.y;
      ac[1][0] += hv.y * wc.x; ac[1][1] += hv.y * wc.y;
      ao[0][0] += hv.x * wo.x; ao[0][1] += hv.x * wo.y;
      ao[1][0] += hv.y * wo.x; ao[1][1] += hv.y * wo.y;
    }
  }

  const float2 bcv  = *(const float2*)(bc + n * Dd + d0);
  const float2 bov  = *(const float2*)(bo + n * Dd + d0);
  const float2 wplo = *(const float2*)(Wp + n * 64 + d0);
  const float2 wphi = *(const float2*)(Wp + n * 64 + 32 + d0);
  const float bpv = bp[n];

  float pp[2];
  #pragma unroll
  for (int r = 0; r < 2; r++) {
    const int b = bt + ty * 2 + r;
    const float xm0  = ac[r][0] + bcv.x;
    const float xm1  = ac[r][1] + bcv.y;
    const float pre0 = ao[r][0] + bov.x;
    const float pre1 = ao[r][1] + bov.y;
    // stable softplus = max(x,0) + log1p(exp(-|x|))
    const float dl0 = fmaxf(pre0, 0.f) + log1pf(expf(-fabsf(pre0)));
    const float dl1 = fmaxf(pre1, 0.f) + log1pf(expf(-fabsf(pre1)));
    *(float2*)(xm_ws + b * 2048 + n * Dd + d0) = make_float2(xm0, xm1);
    *(float2*)(dl_ws + b * 2048 + n * Dd + d0) = make_float2(dl0, dl1);
    pp[r] = xm0 * wplo.x + xm1 * wplo.y + dl0 * wphi.x + dl1 * wphi.y;
  }
  // reduce over the 16 consecutive lanes sharing ty
  #pragma unroll
  for (int r = 0; r < 2; r++) {
    pp[r] += __shfl_xor(pp[r], 1);
    pp[r] += __shfl_xor(pp[r], 2);
    pp[r] += __shfl_xor(pp[r], 4);
    pp[r] += __shfl_xor(pp[r], 8);
  }
  if (tx == 0) {
    #pragma unroll
    for (int r = 0; r < 2; r++) {
      const int b = bt + ty * 2 + r;
      const float ph = 1.f / (1.f + expf(-(pp[r] + bpv)));
      ph_ws[b * 64 + n] = ph;
      out_ph[b * 64 + n] = ph;
    }
  }
}

// ---------------------------------------------------------------------------
// Kernel B v2: pairwise intersection volumes V[b,i,j].
// One block (512 thr, 8 waves) per b.
// ---------------------------------------------------------------------------
__global__ __launch_bounds__(512) void kB(
    const float* __restrict__ xm_ws,
    const float* __restrict__ dl_ws,
    float* __restrict__ out_V)      // [256][64][64]
{
  const int b = blockIdx.x, t = threadIdx.x;
  __shared__ float lo[64][36];
  __shared__ float hi[64][36];
  __shared__ float rvol[64];

  {
    const int n = t >> 3, dd = (t & 7) * 4;
    float4 x = *(const float4*)(xm_ws + b * 2048 + n * Dd + dd);
    float4 g = *(const float4*)(dl_ws + b * 2048 + n * Dd + dd);
    lo[n][dd + 0] = x.x - g.x;  hi[n][dd + 0] = x.x + g.x;
    lo[n][dd + 1] = x.y - g.y;  hi[n][dd + 1] = x.y + g.y;
    lo[n][dd + 2] = x.z - g.z;  hi[n][dd + 2] = x.z + g.z;
    lo[n][dd + 3] = x.w - g.w;  hi[n][dd + 3] = x.w + g.w;
  }
  if (t < 64) {
    const float* dp = dl_ws + b * 2048 + t * Dd;
    float p = 1.f;
    #pragma unroll
    for (int dd = 0; dd < 32; dd++) p *= dp[dd] + EPS;
    rvol[t] = 1.f / p;
  }
  __syncthreads();

  const int i0 = t >> 6;    // wave id -> i uniform per wave
  const int j  = t & 63;
  #pragma unroll 1
  for (int it = 0; it < 8; it++) {
    const int i = i0 + 8 * it;
    float prod = 1.f;
    #pragma unroll
    for (int dd = 0; dd < 32; dd += 4) {
      float4 hj = *(const float4*)&hi[j][dd];
      float4 lj = *(const float4*)&lo[j][dd];
      float4 hv = *(const float4*)&hi[i][dd];   // broadcast
      float4 lv = *(const float4*)&lo[i][dd];   // broadcast
      float v0 = fmaxf(fminf(hv.x, hj.x) - fmaxf(lv.x, lj.x), 0.f) * 0.5f + EPS;
      float v1 = fmaxf(fminf(hv.y, hj.y) - fmaxf(lv.y, lj.y), 0.f) * 0.5f + EPS;
      float v2 = fmaxf(fminf(hv.z, hj.z) - fmaxf(lv.z, lj.z), 0.f) * 0.5f + EPS;
      float v3 = fmaxf(fminf(hv.w, hj.w) - fmaxf(lv.w, lj.w), 0.f) * 0.5f + EPS;
      prod *= v0 * v1 * v2 * v3;
    }
    out_V[b * 4096 + i * 64 + j] = prod * rvol[j];
  }
}

// ---------------------------------------------------------------------------
// Kernel C1 v2: split-K GEMM partials, 64 slices (KSL=128).
//   A = concat([aligned, V]) : [256][8192], W = [W1; W2] : [8192][100]
//   grid (bg=8, s=64) = 512 blocks -> 2 blocks/CU.
// ---------------------------------------------------------------------------
__global__ __launch_bounds__(256) void kC1(
    const float* __restrict__ xm_ws,   // [256][2048]
    const float* __restrict__ dl_ws,   // [256][2048]
    const float* __restrict__ ph_ws,   // [256][64]
    const float* __restrict__ Vb,      // [256][4096] (from d_out)
    const float* __restrict__ W1,      // [4096][100]
    const float* __restrict__ W2,      // [4096][100]
    float* __restrict__ part)          // [64][256][100]
{
  const int bg = blockIdx.x;           // 8 row-groups of 32
  const int s  = blockIdx.y;           // 64 K-slices
  const bool isV = (s >= 32);
  const int m0 = (s & 31) * 128;       // type-local K offset, KSL=128
  const float* __restrict__ W = isV ? W2 : W1;

  __shared__ float Wt[64][132];        // [kk][col]
  __shared__ float At[64][33];         // [kk][row]

  const int t  = threadIdx.x;
  const int tx = t & 15;               // col quads tx, tx+16
  const int ty = t >> 4;               // rows ty*2, ty*2+1

  float acc[2][8] = {};

  const int wrw = t >> 2, wq8 = (t & 3) * 8;       // W: row, granule base
  const int arow = t >> 3, agk = t & 7;            // A: row, kk-octet
  const int brow_s = bg * 32 + arow;

  for (int ch = 0; ch < 2; ch++) {
    const int mbase = m0 + ch * 64;
    __syncthreads();
    // ---- stage W chunk [64][100] ----
    {
      const float* wr = W + (mbase + wrw) * Cc;
      #pragma unroll
      for (int j = 0; j < 8; j++) {
        const int c = (wq8 + j) * 4;
        float4 v = make_float4(0.f, 0.f, 0.f, 0.f);
        if (c < Cc) v = *(const float4*)(wr + c);
        *(float4*)&Wt[wrw][c] = v;
      }
    }
    // ---- stage A chunk [64 kk][32 rows] ----
    {
      const int mk = mbase + agk * 8;
      float4 v0, v1;
      if (!isV) {
        const int nn = mk >> 6, sub = mk & 63;
        const float phv = ph_ws[brow_s * 64 + nn];
        const float* src = (sub < 32)
            ? (xm_ws + brow_s * 2048 + nn * Dd + sub)
            : (dl_ws + brow_s * 2048 + nn * Dd + (sub - 32));
        v0 = *(const float4*)(src);
        v1 = *(const float4*)(src + 4);
        v0.x *= phv; v0.y *= phv; v0.z *= phv; v0.w *= phv;
        v1.x *= phv; v1.y *= phv; v1.z *= phv; v1.w *= phv;
      } else {
        const float* src = Vb + brow_s * 4096 + mk;
        v0 = *(const float4*)(src);
        v1 = *(const float4*)(src + 4);
      }
      const int k8 = agk * 8;
      At[k8 + 0][arow] = v0.x; At[k8 + 1][arow] = v0.y;
      At[k8 + 2][arow] = v0.z; At[k8 + 3][arow] = v0.w;
      At[k8 + 4][arow] = v1.x; At[k8 + 5][arow] = v1.y;
      At[k8 + 6][arow] = v1.z; At[k8 + 7][arow] = v1.w;
    }
    __syncthreads();
    // ---- compute ----
    #pragma unroll 8
    for (int kk = 0; kk < 64; kk++) {
      const float a0 = At[kk][ty * 2];
      const float a1 = At[kk][ty * 2 + 1];
      float4 wlo = *(const float4*)&Wt[kk][tx * 4];
      float4 whi = *(const float4*)&Wt[kk][(tx + 16) * 4];
      acc[0][0] += a0 * wlo.x; acc[0][1] += a0 * wlo.y;
      acc[0][2] += a0 * wlo.z; acc[0][3] += a0 * wlo.w;
      acc[0][4] += a0 * whi.x; acc[0][5] += a0 * whi.y;
      acc[0][6] += a0 * whi.z; acc[0][7] += a0 * whi.w;
      acc[1][0] += a1 * wlo.x; acc[1][1] += a1 * wlo.y;
      acc[1][2] += a1 * wlo.z; acc[1][3] += a1 * wlo.w;
      acc[1][4] += a1 * whi.x; acc[1][5] += a1 * whi.y;
      acc[1][6] += a1 * whi.z; acc[1][7] += a1 * whi.w;
    }
  }

  #pragma unroll
  for (int r = 0; r < 2; r++) {
    const int brow = bg * 32 + ty * 2 + r;
    float* pr = part + (s * 256 + brow) * Cc;
    #pragma unroll
    for (int q = 0; q < 2; q++) {
      const int c0 = (tx + q * 16) * 4;
      if (c0 < Cc) {
        pr[c0 + 0] = acc[r][q * 4 + 0];
        pr[c0 + 1] = acc[r][q * 4 + 1];
        pr[c0 + 2] = acc[r][q * 4 + 2];
        pr[c0 + 3] = acc[r][q * 4 + 3];
      }
    }
  }
}

// ---------------------------------------------------------------------------
// Kernel C2: reduce 64 partials + biases -> y.  grid 100 x 256 threads.
// ---------------------------------------------------------------------------
__global__ __launch_bounds__(256) void kC2(
    const float* __restrict__ part,    // [64][25600]
    const float* __restrict__ b1,
    const float* __restrict__ b2,
    float* __restrict__ out_y)         // [256][100] flat = 25600
{
  const int o = blockIdx.x * 256 + threadIdx.x;   // 0..25599
  const int c = o % Cc;
  float sum = b1[c] + b2[c];
  #pragma unroll
  for (int s = 0; s < 64; s++) sum += part[s * 25600 + o];
  out_y[o] = sum;
}

// ---------------------------------------------------------------------------
extern "C" void kernel_launch(void* const* d_in, const int* in_sizes, int n_in,
                              void* d_out, int out_size, void* d_ws, size_t ws_size,
                              hipStream_t stream) {
  const float* h  = (const float*)d_in[0];
  const float* Wc = (const float*)d_in[1];
  const float* bc = (const float*)d_in[2];
  const float* Wo = (const float*)d_in[3];
  const float* bo = (const float*)d_in[4];
  const float* Wp = (const float*)d_in[5];
  const float* bp = (const float*)d_in[6];
  const float* W1 = (const float*)d_in[7];
  const float* b1 = (const float*)d_in[8];
  const float* W2 = (const float*)d_in[9];
  const float* b2 = (const float*)d_in[10];

  float* out    = (float*)d_out;
  float* out_y  = out;                         // [256][100]
  float* out_ph = out + Bb * Cc;               // [256][64]
  float* out_V  = out + Bb * Cc + Bb * Nn;     // [256][64][64]

  float* xm   = (float*)d_ws;              // 524288 f32 (2 MB)
  float* dl   = xm + Bb * Nn * Dd;         // 524288 f32 (2 MB)
  float* ph   = dl + Bb * Nn * Dd;         // 16384 f32
  float* part = ph + Bb * Nn;              // 64*25600 f32 (6.55 MB)

  kA<<<dim3(Nn, Bb / 32), 256, 0, stream>>>(h, Wc, bc, Wo, bo, Wp, bp,
                                            xm, dl, ph, out_ph);
  kB<<<Bb, 512, 0, stream>>>(xm, dl, out_V);
  kC1<<<dim3(8, 64), 256, 0, stream>>>(xm, dl, ph, (const float*)out_V,
                                       W1, W2, part);
  kC2<<<100, 256, 0, stream>>>(part, b1, b2, out_y);
}

// Round 6
// 71.180 us; speedup vs baseline: 1.1582x; 1.1582x over previous
//
#include <hip/hip_runtime.h>
#include <hip/hip_bf16.h>
#include <cstdint>

// Problem constants (ConceptBoxModel): B=256, L=512, N=64, D=32, C=100
constexpr int Bb = 256, Ll = 512, Nn = 64, Dd = 32, Cc = 100;
constexpr float EPS = 1e-6f;

// ---------------------------------------------------------------------------
// Kernel A v4: x_m = h@Wc + bc ; delta = softplus(h@Wo + bo) ; p_hat
// grid (n=64, bt=4) = 256 blocks, 512 threads, intra-block split-K (2 groups).
// LDS: packed W pairs (wc0,wc1,wo0,wo1) -> inner loop = 2 x ds_read_b128
// per 16 FMA.  Next k-tile global loads prefetched into regs under compute.
// ---------------------------------------------------------------------------
__global__ __launch_bounds__(512) void kA(
    const float* __restrict__ h,    // [256][512]
    const float* __restrict__ Wc,   // [64][512][32]
    const float* __restrict__ bc,   // [64][32]
    const float* __restrict__ Wo,
    const float* __restrict__ bo,
    const float* __restrict__ Wp,   // [64][64]
    const float* __restrict__ bp,   // [64]
    float* __restrict__ xm_ws,      // [256][64][32]
    float* __restrict__ dl_ws,      // [256][64][32]
    float* __restrict__ ph_ws,      // [256][64]
    float* __restrict__ out_ph)     // [256][64]
{
  const int n  = blockIdx.x;
  const int bt = blockIdx.y * 64;
  const int t  = threadIdx.x;     // 0..511
  const int kg = t >> 8;          // K-group 0/1
  const int tl = t & 255;
  const int tx = tl & 15;         // d-pair: d0 = 2*tx
  const int ty = tl >> 4;         // rows ty*4 .. ty*4+3
  const int d0 = tx * 2;

  __shared__ union USm {
    struct {
      float hsT[2][32][68];       // [kg][kk][row]
      float wpk[2][32][68];       // [kg][kk][pair*4]: wc0 wc1 wo0 wo1
    } s;
    float red[16][264];           // cross-group reduce buffer
  } u;

  float acc[4][4] = {};           // [row][wc0,wc1,wo0,wo1]

  const int sr  = tl >> 2, sk8 = (tl & 3) * 8;   // h staging: row, kk octet
  const int wkk = tl >> 3, wd  = (tl & 7) * 4;   // W staging: kk, d quad
  const float* wcb = Wc + n * (Ll * Dd);
  const float* wob = Wo + n * (Ll * Dd);

  // ---- load tile 0 into regs ----
  float4 h0, h1, wv, ov;
  {
    const int k0 = kg * 256;
    const float* hp = h + (bt + sr) * Ll + k0 + sk8;
    h0 = *(const float4*)(hp);
    h1 = *(const float4*)(hp + 4);
    wv = *(const float4*)(wcb + (k0 + wkk) * Dd + wd);
    ov = *(const float4*)(wob + (k0 + wkk) * Dd + wd);
  }

  for (int t8 = 0; t8 < 8; t8++) {
    __syncthreads();   // previous tile's readers done
    // ---- regs -> LDS ----
    u.s.hsT[kg][sk8 + 0][sr] = h0.x; u.s.hsT[kg][sk8 + 1][sr] = h0.y;
    u.s.hsT[kg][sk8 + 2][sr] = h0.z; u.s.hsT[kg][sk8 + 3][sr] = h0.w;
    u.s.hsT[kg][sk8 + 4][sr] = h1.x; u.s.hsT[kg][sk8 + 5][sr] = h1.y;
    u.s.hsT[kg][sk8 + 6][sr] = h1.z; u.s.hsT[kg][sk8 + 7][sr] = h1.w;
    *(float4*)&u.s.wpk[kg][wkk][(wd >> 1) * 4] =
        make_float4(wv.x, wv.y, ov.x, ov.y);
    *(float4*)&u.s.wpk[kg][wkk][(wd >> 1) * 4 + 4] =
        make_float4(wv.z, wv.w, ov.z, ov.w);
    __syncthreads();
    // ---- prefetch next tile (hidden under compute) ----
    if (t8 < 7) {
      const int k0 = kg * 256 + (t8 + 1) * 32;
      const float* hp = h + (bt + sr) * Ll + k0 + sk8;
      h0 = *(const float4*)(hp);
      h1 = *(const float4*)(hp + 4);
      wv = *(const float4*)(wcb + (k0 + wkk) * Dd + wd);
      ov = *(const float4*)(wob + (k0 + wkk) * Dd + wd);
    }
    // ---- compute ----
    #pragma unroll
    for (int kk = 0; kk < 32; kk++) {
      const float4 hv = *(const float4*)&u.s.hsT[kg][kk][ty * 4];
      const float4 wp = *(const float4*)&u.s.wpk[kg][kk][tx * 4];
      acc[0][0] += hv.x * wp.x; acc[0][1] += hv.x * wp.y;
      acc[0][2] += hv.x * wp.z; acc[0][3] += hv.x * wp.w;
      acc[1][0] += hv.y * wp.x; acc[1][1] += hv.y * wp.y;
      acc[1][2] += hv.y * wp.z; acc[1][3] += hv.y * wp.w;
      acc[2][0] += hv.z * wp.x; acc[2][1] += hv.z * wp.y;
      acc[2][2] += hv.z * wp.z; acc[2][3] += hv.z * wp.w;
      acc[3][0] += hv.w * wp.x; acc[3][1] += hv.w * wp.y;
      acc[3][2] += hv.w * wp.z; acc[3][3] += hv.w * wp.w;
    }
  }

  // ---- cross-group reduction (group 1 -> LDS -> group 0) ----
  __syncthreads();
  if (kg == 1) {
    #pragma unroll
    for (int r = 0; r < 4; r++) {
      #pragma unroll
      for (int c = 0; c < 4; c++) u.red[r * 4 + c][tl] = acc[r][c];
    }
  }
  __syncthreads();
  if (kg == 0) {
    const float2 bcv  = *(const float2*)(bc + n * Dd + d0);
    const float2 bov  = *(const float2*)(bo + n * Dd + d0);
    const float2 wplo = *(const float2*)(Wp + n * 64 + d0);
    const float2 wphi = *(const float2*)(Wp + n * 64 + 32 + d0);
    const float bpv = bp[n];
    #pragma unroll
    for (int r = 0; r < 4; r++) {
      const int b = bt + ty * 4 + r;
      const float xm0  = acc[r][0] + u.red[r * 4 + 0][tl] + bcv.x;
      const float xm1  = acc[r][1] + u.red[r * 4 + 1][tl] + bcv.y;
      const float pre0 = acc[r][2] + u.red[r * 4 + 2][tl] + bov.x;
      const float pre1 = acc[r][3] + u.red[r * 4 + 3][tl] + bov.y;
      // stable softplus = max(x,0) + log1p(exp(-|x|))
      const float dl0 = fmaxf(pre0, 0.f) + log1pf(expf(-fabsf(pre0)));
      const float dl1 = fmaxf(pre1, 0.f) + log1pf(expf(-fabsf(pre1)));
      *(float2*)(xm_ws + b * 2048 + n * Dd + d0) = make_float2(xm0, xm1);
      *(float2*)(dl_ws + b * 2048 + n * Dd + d0) = make_float2(dl0, dl1);
      float pp = xm0 * wplo.x + xm1 * wplo.y + dl0 * wphi.x + dl1 * wphi.y;
      pp += __shfl_xor(pp, 1);
      pp += __shfl_xor(pp, 2);
      pp += __shfl_xor(pp, 4);
      pp += __shfl_xor(pp, 8);
      if (tx == 0) {
        const float ph = 1.f / (1.f + expf(-(pp + bpv)));
        ph_ws[b * 64 + n] = ph;
        out_ph[b * 64 + n] = ph;
      }
    }
  }
}

// ---------------------------------------------------------------------------
// Kernel B: pairwise intersection volumes V[b,i,j].  One block per b.
// ---------------------------------------------------------------------------
__global__ __launch_bounds__(256) void kB(
    const float* __restrict__ xm_ws,
    const float* __restrict__ dl_ws,
    float* __restrict__ out_V)      // [256][64][64]
{
  const int b = blockIdx.x, t = threadIdx.x;
  __shared__ float lo[64][36];
  __shared__ float hi[64][36];
  __shared__ float rvol[64];

  {
    const int n = t >> 2, dd = (t & 3) * 8;
    const float* xp = xm_ws + b * 2048 + n * Dd + dd;
    const float* dp = dl_ws + b * 2048 + n * Dd + dd;
    #pragma unroll
    for (int i = 0; i < 8; i += 4) {
      float4 x = *(const float4*)(xp + i);
      float4 g = *(const float4*)(dp + i);
      lo[n][dd + i + 0] = x.x - g.x;  hi[n][dd + i + 0] = x.x + g.x;
      lo[n][dd + i + 1] = x.y - g.y;  hi[n][dd + i + 1] = x.y + g.y;
      lo[n][dd + i + 2] = x.z - g.z;  hi[n][dd + i + 2] = x.z + g.z;
      lo[n][dd + i + 3] = x.w - g.w;  hi[n][dd + i + 3] = x.w + g.w;
    }
  }
  if (t < 64) {
    const float* dp = dl_ws + b * 2048 + t * Dd;
    float p = 1.f;
    #pragma unroll
    for (int dd = 0; dd < 32; dd++) p *= dp[dd] + EPS;
    rvol[t] = 1.f / p;
  }
  __syncthreads();

  const int i0 = t >> 6;    // wave id -> i uniform per wave
  const int j  = t & 63;
  #pragma unroll 1
  for (int it = 0; it < 16; it++) {
    const int i = i0 + 4 * it;
    float prod = 1.f;
    #pragma unroll
    for (int dd = 0; dd < 32; dd += 4) {
      float4 hj = *(const float4*)&hi[j][dd];
      float4 lj = *(const float4*)&lo[j][dd];
      float4 hv = *(const float4*)&hi[i][dd];   // broadcast
      float4 lv = *(const float4*)&lo[i][dd];   // broadcast
      float v0 = fmaxf(fminf(hv.x, hj.x) - fmaxf(lv.x, lj.x), 0.f) * 0.5f + EPS;
      float v1 = fmaxf(fminf(hv.y, hj.y) - fmaxf(lv.y, lj.y), 0.f) * 0.5f + EPS;
      float v2 = fmaxf(fminf(hv.z, hj.z) - fmaxf(lv.z, lj.z), 0.f) * 0.5f + EPS;
      float v3 = fmaxf(fminf(hv.w, hj.w) - fmaxf(lv.w, lj.w), 0.f) * 0.5f + EPS;
      prod *= v0 * v1 * v2 * v3;
    }
    out_V[b * 4096 + i * 64 + j] = prod * rvol[j];
  }
}

// ---------------------------------------------------------------------------
// Kernel C1: split-K GEMM partials (32 slices, KSL=256) + reg prefetch.
//   A = concat([aligned, V]) : [256][8192], W = [W1; W2] : [8192][100]
// ---------------------------------------------------------------------------
__global__ __launch_bounds__(256) void kC1(
    const float* __restrict__ xm_ws,   // [256][2048]
    const float* __restrict__ dl_ws,   // [256][2048]
    const float* __restrict__ ph_ws,   // [256][64]
    const float* __restrict__ Vb,      // [256][4096] (from d_out)
    const float* __restrict__ W1,      // [4096][100]
    const float* __restrict__ W2,      // [4096][100]
    float* __restrict__ part)          // [32][256][100]
{
  const int bg = blockIdx.x;           // 8 row-groups of 32
  const int s  = blockIdx.y;           // 32 K-slices
  const bool isV = (s >= 16);
  const int m0 = (s & 15) * 256;       // type-local K offset
  const float* __restrict__ W = isV ? W2 : W1;

  __shared__ float Wt[64][132];        // [kk][col]
  __shared__ float At[64][33];         // [kk][row]

  const int t  = threadIdx.x;
  const int tx = t & 15;               // col quads tx, tx+16
  const int ty = t >> 4;               // rows ty*2, ty*2+1

  float acc[2][8] = {};

  const int wrw = t >> 2, wq8 = (t & 3) * 8;       // W: row, granule base
  const int arow = t >> 3, agk = t & 7;            // A: row, kk-octet
  const int brow_s = bg * 32 + arow;

  // ---- chunk loaders into regs ----
  float4 wreg[8];
  float4 a0, a1;
  auto load_chunk = [&](int mbase) {
    const float* wr = W + (mbase + wrw) * Cc;
    #pragma unroll
    for (int j = 0; j < 8; j++) {
      const int c = (wq8 + j) * 4;
      wreg[j] = (c < Cc) ? *(const float4*)(wr + c)
                         : make_float4(0.f, 0.f, 0.f, 0.f);
    }
    const int mk = mbase + agk * 8;
    if (!isV) {
      const int nn = mk >> 6, sub = mk & 63;
      const float phv = ph_ws[brow_s * 64 + nn];
      const float* src = (sub < 32)
          ? (xm_ws + brow_s * 2048 + nn * Dd + sub)
          : (dl_ws + brow_s * 2048 + nn * Dd + (sub - 32));
      a0 = *(const float4*)(src);
      a1 = *(const float4*)(src + 4);
      a0.x *= phv; a0.y *= phv; a0.z *= phv; a0.w *= phv;
      a1.x *= phv; a1.y *= phv; a1.z *= phv; a1.w *= phv;
    } else {
      const float* src = Vb + brow_s * 4096 + mk;
      a0 = *(const float4*)(src);
      a1 = *(const float4*)(src + 4);
    }
  };

  load_chunk(m0);
  for (int ch = 0; ch < 4; ch++) {
    __syncthreads();
    // ---- regs -> LDS ----
    #pragma unroll
    for (int j = 0; j < 8; j++) {
      const int c = (wq8 + j) * 4;
      if (c < Cc) *(float4*)&Wt[wrw][c] = wreg[j];
    }
    {
      const int k8 = agk * 8;
      At[k8 + 0][arow] = a0.x; At[k8 + 1][arow] = a0.y;
      At[k8 + 2][arow] = a0.z; At[k8 + 3][arow] = a0.w;
      At[k8 + 4][arow] = a1.x; At[k8 + 5][arow] = a1.y;
      At[k8 + 6][arow] = a1.z; At[k8 + 7][arow] = a1.w;
    }
    __syncthreads();
    // ---- prefetch next chunk ----
    if (ch < 3) load_chunk(m0 + (ch + 1) * 64);
    // ---- compute ----
    #pragma unroll 8
    for (int kk = 0; kk < 64; kk++) {
      const float av0 = At[kk][ty * 2];
      const float av1 = At[kk][ty * 2 + 1];
      float4 wlo = *(const float4*)&Wt[kk][tx * 4];
      float4 whi = *(const float4*)&Wt[kk][(tx + 16) * 4];
      acc[0][0] += av0 * wlo.x; acc[0][1] += av0 * wlo.y;
      acc[0][2] += av0 * wlo.z; acc[0][3] += av0 * wlo.w;
      acc[0][4] += av0 * whi.x; acc[0][5] += av0 * whi.y;
      acc[0][6] += av0 * whi.z; acc[0][7] += av0 * whi.w;
      acc[1][0] += av1 * wlo.x; acc[1][1] += av1 * wlo.y;
      acc[1][2] += av1 * wlo.z; acc[1][3] += av1 * wlo.w;
      acc[1][4] += av1 * whi.x; acc[1][5] += av1 * whi.y;
      acc[1][6] += av1 * whi.z; acc[1][7] += av1 * whi.w;
    }
  }

  #pragma unroll
  for (int r = 0; r < 2; r++) {
    const int brow = bg * 32 + ty * 2 + r;
    float* pr = part + (s * 256 + brow) * Cc;
    #pragma unroll
    for (int q = 0; q < 2; q++) {
      const int c0 = (tx + q * 16) * 4;
      if (c0 < Cc) {
        pr[c0 + 0] = acc[r][q * 4 + 0];
        pr[c0 + 1] = acc[r][q * 4 + 1];
        pr[c0 + 2] = acc[r][q * 4 + 2];
        pr[c0 + 3] = acc[r][q * 4 + 3];
      }
    }
  }
}

// ---------------------------------------------------------------------------
// Kernel C2: reduce 32 partials + biases -> y.  grid 100 x 256 threads.
// ---------------------------------------------------------------------------
__global__ __launch_bounds__(256) void kC2(
    const float* __restrict__ part,    // [32][25600]
    const float* __restrict__ b1,
    const float* __restrict__ b2,
    float* __restrict__ out_y)         // [256][100] flat = 25600
{
  const int o = blockIdx.x * 256 + threadIdx.x;   // 0..25599
  const int c = o % Cc;
  float sum = b1[c] + b2[c];
  #pragma unroll
  for (int s = 0; s < 32; s++) sum += part[s * 25600 + o];
  out_y[o] = sum;
}

// ---------------------------------------------------------------------------
extern "C" void kernel_launch(void* const* d_in, const int* in_sizes, int n_in,
                              void* d_out, int out_size, void* d_ws, size_t ws_size,
                              hipStream_t stream) {
  const float* h  = (const float*)d_in[0];
  const float* Wc = (const float*)d_in[1];
  const float* bc = (const float*)d_in[2];
  const float* Wo = (const float*)d_in[3];
  const float* bo = (const float*)d_in[4];
  const float* Wp = (const float*)d_in[5];
  const float* bp = (const float*)d_in[6];
  const float* W1 = (const float*)d_in[7];
  const float* b1 = (const float*)d_in[8];
  const float* W2 = (const float*)d_in[9];
  const float* b2 = (const float*)d_in[10];

  float* out    = (float*)d_out;
  float* out_y  = out;                         // [256][100]
  float* out_ph = out + Bb * Cc;               // [256][64]
  float* out_V  = out + Bb * Cc + Bb * Nn;     // [256][64][64]

  float* xm   = (float*)d_ws;              // 524288 f32 (2 MB)
  float* dl   = xm + Bb * Nn * Dd;         // 524288 f32 (2 MB)
  float* ph   = dl + Bb * Nn * Dd;         // 16384 f32
  float* part = ph + Bb * Nn;              // 32*25600 f32 (3.28 MB)

  kA<<<dim3(Nn, Bb / 64), 512, 0, stream>>>(h, Wc, bc, Wo, bo, Wp, bp,
                                            xm, dl, ph, out_ph);
  kB<<<Bb, 256, 0, stream>>>(xm, dl, out_V);
  kC1<<<dim3(8, 32), 256, 0, stream>>>(xm, dl, ph, (const float*)out_V,
                                       W1, W2, part);
  kC2<<<100, 256, 0, stream>>>(part, b1, b2, out_y);
}

// Round 7
// 52.735 us; speedup vs baseline: 1.5633x; 1.3498x over previous
//
#include <hip/hip_runtime.h>
#include <hip/hip_bf16.h>
#include <cstdint>

// Problem constants (ConceptBoxModel): B=256, L=512, N=64, D=32, C=100
constexpr int Bb = 256, Ll = 512, Nn = 64, Dd = 32, Cc = 100;
constexpr float EPS = 1e-6f;

typedef __attribute__((ext_vector_type(8))) short short8;   // 8 bf16 (4 VGPRs)
typedef __attribute__((ext_vector_type(4))) float f32x4;    // MFMA C/D frag

__device__ __forceinline__ unsigned short f2bf(float f) {
  union { float f; uint32_t u; } v; v.f = f;
  uint32_t r = v.u + 0x7FFFu + ((v.u >> 16) & 1u);   // RNE
  return (unsigned short)(r >> 16);
}

// ---------------------------------------------------------------------------
// Kernel A v5 (MFMA): x_m = h@Wc + bc ; delta = softplus(h@Wo + bo) ; p_hat
// grid (n=64 fast, bt=4) = 256 blocks x 256 thr (4 waves).
// Per block: one n, 64 b-rows, 64 out-cols (32 xm | 32 dl), K=512 in 8 chunks.
// Wave w owns rows w*16..w*16+15; 4 N-frags x 2 K-steps per chunk = 8 MFMA.
// A/B staged in LDS as bf16 with identical per-lane k-order (order cancels).
// C/D layout (m89-verified): col=lane&15, row=(lane>>4)*4+reg.
// ---------------------------------------------------------------------------
__global__ __launch_bounds__(256) void kA(
    const float* __restrict__ h,    // [256][512]
    const float* __restrict__ Wc,   // [64][512][32]
    const float* __restrict__ bc,   // [64][32]
    const float* __restrict__ Wo,
    const float* __restrict__ bo,
    const float* __restrict__ Wp,   // [64][64]
    const float* __restrict__ bp,   // [64]
    float* __restrict__ xm_ws,      // [256][64][32]
    float* __restrict__ dl_ws,      // [256][64][32]
    float* __restrict__ ph_ws,      // [256][64]
    float* __restrict__ out_ph)     // [256][64]
{
  const int n  = blockIdx.x;
  const int bt = blockIdx.y * 64;
  const int t  = threadIdx.x;
  const int w  = t >> 6, l = t & 63;
  const int lr = l & 15, lg = l >> 4;

  __shared__ unsigned short hb[64][64];    // [row][k] bf16, 128B rows
  __shared__ unsigned short wbT[64][72];   // [col][k] bf16, 144B rows (pad 72)

  f32x4 acc[4] = {};   // nf=0,1 -> xm cols 0-31 ; nf=2,3 -> dl cols 0-31

  // staging maps (exact covers: h 64x64, W 64x32 x2)
  const int hr = t >> 2,        hc = (t & 3) * 16;   // h: row, 16-k run
  const int wk = (t >> 3) * 2,  wcq = (t & 7) * 4;   // W: 2 k-rows, 4 cols
  const float* hsrc  = h  + (bt + hr) * Ll + hc;
  const float* wcsrc = Wc + n * (Ll * Dd) + wk * Dd + wcq;
  const float* wosrc = Wo + n * (Ll * Dd) + wk * Dd + wcq;

  float4 hp0, hp1, hp2, hp3, c0, c1, o0, o1;
  auto fetch = [&](int k0) {
    const float* hs = hsrc + k0;
    hp0 = *(const float4*)(hs);
    hp1 = *(const float4*)(hs + 4);
    hp2 = *(const float4*)(hs + 8);
    hp3 = *(const float4*)(hs + 12);
    const float* ws = wcsrc + k0 * Dd;
    c0 = *(const float4*)(ws);
    c1 = *(const float4*)(ws + Dd);
    const float* os = wosrc + k0 * Dd;
    o0 = *(const float4*)(os);
    o1 = *(const float4*)(os + Dd);
  };

  fetch(0);
  for (int ch = 0; ch < 8; ch++) {
    __syncthreads();   // previous chunk's readers done
    // ---- h tile -> LDS bf16 (16 consecutive k per thread) ----
    {
      unsigned short* hd = &hb[hr][hc];
      hd[0]  = f2bf(hp0.x); hd[1]  = f2bf(hp0.y);
      hd[2]  = f2bf(hp0.z); hd[3]  = f2bf(hp0.w);
      hd[4]  = f2bf(hp1.x); hd[5]  = f2bf(hp1.y);
      hd[6]  = f2bf(hp1.z); hd[7]  = f2bf(hp1.w);
      hd[8]  = f2bf(hp2.x); hd[9]  = f2bf(hp2.y);
      hd[10] = f2bf(hp2.z); hd[11] = f2bf(hp2.w);
      hd[12] = f2bf(hp3.x); hd[13] = f2bf(hp3.y);
      hd[14] = f2bf(hp3.z); hd[15] = f2bf(hp3.w);
    }
    // ---- W tiles -> LDS transposed: wbT[col][k] (k-pair packed b32) ----
    {
      const float* c0p = &c0.x; const float* c1p = &c1.x;
      const float* o0p = &o0.x; const float* o1p = &o1.x;
      #pragma unroll
      for (int i = 0; i < 4; i++) {
        unsigned int pc = (unsigned int)f2bf(c0p[i]) |
                          ((unsigned int)f2bf(c1p[i]) << 16);
        *(unsigned int*)&wbT[wcq + i][wk] = pc;
        unsigned int po = (unsigned int)f2bf(o0p[i]) |
                          ((unsigned int)f2bf(o1p[i]) << 16);
        *(unsigned int*)&wbT[32 + wcq + i][wk] = po;
      }
    }
    __syncthreads();
    // ---- prefetch next chunk under compute ----
    if (ch < 7) fetch((ch + 1) * 64);
    // ---- MFMA ----
    const int arow = w * 16 + lr;
    #pragma unroll
    for (int ks = 0; ks < 2; ks++) {
      const int ko = ks * 32 + lg * 8;
      const short8 av = *(const short8*)&hb[arow][ko];
      #pragma unroll
      for (int nf = 0; nf < 4; nf++) {
        const short8 bv = *(const short8*)&wbT[nf * 16 + lr][ko];
        acc[nf] = __builtin_amdgcn_mfma_f32_16x16x32_bf16(av, bv, acc[nf],
                                                          0, 0, 0);
      }
    }
  }

  // ---- epilogue: bias, softplus, p_hat, stores ----
  const float bc0 = bc[n * Dd + lr],      bc1 = bc[n * Dd + 16 + lr];
  const float bo0 = bo[n * Dd + lr],      bo1 = bo[n * Dd + 16 + lr];
  const float wp0 = Wp[n * 64 + lr],      wp1 = Wp[n * 64 + 16 + lr];
  const float wp2 = Wp[n * 64 + 32 + lr], wp3 = Wp[n * 64 + 48 + lr];
  const float bpv = bp[n];

  #pragma unroll
  for (int q = 0; q < 4; q++) {
    const int b = bt + w * 16 + lg * 4 + q;
    const float xm0  = acc[0][q] + bc0;
    const float xm1  = acc[1][q] + bc1;
    const float pre0 = acc[2][q] + bo0;
    const float pre1 = acc[3][q] + bo1;
    // stable softplus = max(x,0) + log1p(exp(-|x|))
    const float dl0 = fmaxf(pre0, 0.f) + log1pf(expf(-fabsf(pre0)));
    const float dl1 = fmaxf(pre1, 0.f) + log1pf(expf(-fabsf(pre1)));
    float* xp = xm_ws + b * 2048 + n * Dd;
    float* dp = dl_ws + b * 2048 + n * Dd;
    xp[lr] = xm0;  xp[16 + lr] = xm1;
    dp[lr] = dl0;  dp[16 + lr] = dl1;
    float pp = xm0 * wp0 + xm1 * wp1 + dl0 * wp2 + dl1 * wp3;
    pp += __shfl_xor(pp, 1);
    pp += __shfl_xor(pp, 2);
    pp += __shfl_xor(pp, 4);
    pp += __shfl_xor(pp, 8);
    if (lr == 0) {
      const float ph = 1.f / (1.f + expf(-(pp + bpv)));
      ph_ws[b * 64 + n] = ph;
      out_ph[b * 64 + n] = ph;
    }
  }
}

// ---------------------------------------------------------------------------
// Kernel B: pairwise intersection volumes V[b,i,j].  One block per b.
// ---------------------------------------------------------------------------
__global__ __launch_bounds__(256) void kB(
    const float* __restrict__ xm_ws,
    const float* __restrict__ dl_ws,
    float* __restrict__ out_V)      // [256][64][64]
{
  const int b = blockIdx.x, t = threadIdx.x;
  __shared__ float lo[64][36];
  __shared__ float hi[64][36];
  __shared__ float rvol[64];

  {
    const int n = t >> 2, dd = (t & 3) * 8;
    const float* xp = xm_ws + b * 2048 + n * Dd + dd;
    const float* dp = dl_ws + b * 2048 + n * Dd + dd;
    #pragma unroll
    for (int i = 0; i < 8; i += 4) {
      float4 x = *(const float4*)(xp + i);
      float4 g = *(const float4*)(dp + i);
      lo[n][dd + i + 0] = x.x - g.x;  hi[n][dd + i + 0] = x.x + g.x;
      lo[n][dd + i + 1] = x.y - g.y;  hi[n][dd + i + 1] = x.y + g.y;
      lo[n][dd + i + 2] = x.z - g.z;  hi[n][dd + i + 2] = x.z + g.z;
      lo[n][dd + i + 3] = x.w - g.w;  hi[n][dd + i + 3] = x.w + g.w;
    }
  }
  if (t < 64) {
    const float* dp = dl_ws + b * 2048 + t * Dd;
    float p = 1.f;
    #pragma unroll
    for (int dd = 0; dd < 32; dd++) p *= dp[dd] + EPS;
    rvol[t] = 1.f / p;
  }
  __syncthreads();

  const int i0 = t >> 6;    // wave id -> i uniform per wave
  const int j  = t & 63;
  #pragma unroll 1
  for (int it = 0; it < 16; it++) {
    const int i = i0 + 4 * it;
    float prod = 1.f;
    #pragma unroll
    for (int dd = 0; dd < 32; dd += 4) {
      float4 hj = *(const float4*)&hi[j][dd];
      float4 lj = *(const float4*)&lo[j][dd];
      float4 hv = *(const float4*)&hi[i][dd];   // broadcast
      float4 lv = *(const float4*)&lo[i][dd];   // broadcast
      float v0 = fmaxf(fminf(hv.x, hj.x) - fmaxf(lv.x, lj.x), 0.f) * 0.5f + EPS;
      float v1 = fmaxf(fminf(hv.y, hj.y) - fmaxf(lv.y, lj.y), 0.f) * 0.5f + EPS;
      float v2 = fmaxf(fminf(hv.z, hj.z) - fmaxf(lv.z, lj.z), 0.f) * 0.5f + EPS;
      float v3 = fmaxf(fminf(hv.w, hj.w) - fmaxf(lv.w, lj.w), 0.f) * 0.5f + EPS;
      prod *= v0 * v1 * v2 * v3;
    }
    out_V[b * 4096 + i * 64 + j] = prod * rvol[j];
  }
}

// ---------------------------------------------------------------------------
// Kernel C1: split-K GEMM partials (32 slices, KSL=256) + reg prefetch.
//   A = concat([aligned, V]) : [256][8192], W = [W1; W2] : [8192][100]
// ---------------------------------------------------------------------------
__global__ __launch_bounds__(256) void kC1(
    const float* __restrict__ xm_ws,   // [256][2048]
    const float* __restrict__ dl_ws,   // [256][2048]
    const float* __restrict__ ph_ws,   // [256][64]
    const float* __restrict__ Vb,      // [256][4096] (from d_out)
    const float* __restrict__ W1,      // [4096][100]
    const float* __restrict__ W2,      // [4096][100]
    float* __restrict__ part)          // [32][256][100]
{
  const int bg = blockIdx.x;           // 8 row-groups of 32
  const int s  = blockIdx.y;           // 32 K-slices
  const bool isV = (s >= 16);
  const int m0 = (s & 15) * 256;       // type-local K offset
  const float* __restrict__ W = isV ? W2 : W1;

  __shared__ float Wt[64][132];        // [kk][col]
  __shared__ float At[64][33];         // [kk][row]

  const int t  = threadIdx.x;
  const int tx = t & 15;               // col quads tx, tx+16
  const int ty = t >> 4;               // rows ty*2, ty*2+1

  float acc[2][8] = {};

  const int wrw = t >> 2, wq8 = (t & 3) * 8;       // W: row, granule base
  const int arow = t >> 3, agk = t & 7;            // A: row, kk-octet
  const int brow_s = bg * 32 + arow;

  float4 wreg[8];
  float4 a0, a1;
  auto load_chunk = [&](int mbase) {
    const float* wr = W + (mbase + wrw) * Cc;
    #pragma unroll
    for (int j = 0; j < 8; j++) {
      const int c = (wq8 + j) * 4;
      wreg[j] = (c < Cc) ? *(const float4*)(wr + c)
                         : make_float4(0.f, 0.f, 0.f, 0.f);
    }
    const int mk = mbase + agk * 8;
    if (!isV) {
      const int nn = mk >> 6, sub = mk & 63;
      const float phv = ph_ws[brow_s * 64 + nn];
      const float* src = (sub < 32)
          ? (xm_ws + brow_s * 2048 + nn * Dd + sub)
          : (dl_ws + brow_s * 2048 + nn * Dd + (sub - 32));
      a0 = *(const float4*)(src);
      a1 = *(const float4*)(src + 4);
      a0.x *= phv; a0.y *= phv; a0.z *= phv; a0.w *= phv;
      a1.x *= phv; a1.y *= phv; a1.z *= phv; a1.w *= phv;
    } else {
      const float* src = Vb + brow_s * 4096 + mk;
      a0 = *(const float4*)(src);
      a1 = *(const float4*)(src + 4);
    }
  };

  load_chunk(m0);
  for (int ch = 0; ch < 4; ch++) {
    __syncthreads();
    #pragma unroll
    for (int j = 0; j < 8; j++) {
      const int c = (wq8 + j) * 4;
      if (c < Cc) *(float4*)&Wt[wrw][c] = wreg[j];
    }
    {
      const int k8 = agk * 8;
      At[k8 + 0][arow] = a0.x; At[k8 + 1][arow] = a0.y;
      At[k8 + 2][arow] = a0.z; At[k8 + 3][arow] = a0.w;
      At[k8 + 4][arow] = a1.x; At[k8 + 5][arow] = a1.y;
      At[k8 + 6][arow] = a1.z; At[k8 + 7][arow] = a1.w;
    }
    __syncthreads();
    if (ch < 3) load_chunk(m0 + (ch + 1) * 64);
    #pragma unroll 8
    for (int kk = 0; kk < 64; kk++) {
      const float av0 = At[kk][ty * 2];
      const float av1 = At[kk][ty * 2 + 1];
      float4 wlo = *(const float4*)&Wt[kk][tx * 4];
      float4 whi = *(const float4*)&Wt[kk][(tx + 16) * 4];
      acc[0][0] += av0 * wlo.x; acc[0][1] += av0 * wlo.y;
      acc[0][2] += av0 * wlo.z; acc[0][3] += av0 * wlo.w;
      acc[0][4] += av0 * whi.x; acc[0][5] += av0 * whi.y;
      acc[0][6] += av0 * whi.z; acc[0][7] += av0 * whi.w;
      acc[1][0] += av1 * wlo.x; acc[1][1] += av1 * wlo.y;
      acc[1][2] += av1 * wlo.z; acc[1][3] += av1 * wlo.w;
      acc[1][4] += av1 * whi.x; acc[1][5] += av1 * whi.y;
      acc[1][6] += av1 * whi.z; acc[1][7] += av1 * whi.w;
    }
  }

  #pragma unroll
  for (int r = 0; r < 2; r++) {
    const int brow = bg * 32 + ty * 2 + r;
    float* pr = part + (s * 256 + brow) * Cc;
    #pragma unroll
    for (int q = 0; q < 2; q++) {
      const int c0 = (tx + q * 16) * 4;
      if (c0 < Cc) {
        pr[c0 + 0] = acc[r][q * 4 + 0];
        pr[c0 + 1] = acc[r][q * 4 + 1];
        pr[c0 + 2] = acc[r][q * 4 + 2];
        pr[c0 + 3] = acc[r][q * 4 + 3];
      }
    }
  }
}

// ---------------------------------------------------------------------------
// Kernel C2: reduce 32 partials + biases -> y.  grid 100 x 256 threads.
// ---------------------------------------------------------------------------
__global__ __launch_bounds__(256) void kC2(
    const float* __restrict__ part,    // [32][25600]
    const float* __restrict__ b1,
    const float* __restrict__ b2,
    float* __restrict__ out_y)         // [256][100] flat = 25600
{
  const int o = blockIdx.x * 256 + threadIdx.x;   // 0..25599
  const int c = o % Cc;
  float sum = b1[c] + b2[c];
  #pragma unroll
  for (int s = 0; s < 32; s++) sum += part[s * 25600 + o];
  out_y[o] = sum;
}

// ---------------------------------------------------------------------------
extern "C" void kernel_launch(void* const* d_in, const int* in_sizes, int n_in,
                              void* d_out, int out_size, void* d_ws, size_t ws_size,
                              hipStream_t stream) {
  const float* h  = (const float*)d_in[0];
  const float* Wc = (const float*)d_in[1];
  const float* bc = (const float*)d_in[2];
  const float* Wo = (const float*)d_in[3];
  const float* bo = (const float*)d_in[4];
  const float* Wp = (const float*)d_in[5];
  const float* bp = (const float*)d_in[6];
  const float* W1 = (const float*)d_in[7];
  const float* b1 = (const float*)d_in[8];
  const float* W2 = (const float*)d_in[9];
  const float* b2 = (const float*)d_in[10];

  float* out    = (float*)d_out;
  float* out_y  = out;                         // [256][100]
  float* out_ph = out + Bb * Cc;               // [256][64]
  float* out_V  = out + Bb * Cc + Bb * Nn;     // [256][64][64]

  float* xm   = (float*)d_ws;              // 524288 f32 (2 MB)
  float* dl   = xm + Bb * Nn * Dd;         // 524288 f32 (2 MB)
  float* ph   = dl + Bb * Nn * Dd;         // 16384 f32
  float* part = ph + Bb * Nn;              // 32*25600 f32 (3.28 MB)

  kA<<<dim3(Nn, Bb / 64), 256, 0, stream>>>(h, Wc, bc, Wo, bo, Wp, bp,
                                            xm, dl, ph, out_ph);
  kB<<<Bb, 256, 0, stream>>>(xm, dl, out_V);
  kC1<<<dim3(8, 32), 256, 0, stream>>>(xm, dl, ph, (const float*)out_V,
                                       W1, W2, part);
  kC2<<<100, 256, 0, stream>>>(part, b1, b2, out_y);
}